// Round 8
// baseline (213.163 us; speedup 1.0000x reference)
//
#include <hip/hip_runtime.h>
#include <hip/hip_bf16.h>
#include <stdint.h>

typedef float  f32x4  __attribute__((ext_vector_type(4)));
typedef __bf16 bf16x8 __attribute__((ext_vector_type(8)));
typedef __bf16 bf16x4 __attribute__((ext_vector_type(4)));
typedef short  s16x8  __attribute__((ext_vector_type(8)));

static constexpr int Bc = 16, Sc = 512, Hc = 768, NSPAN = 4068;
static constexpr int BK = 32, KS = Hc / BK; // 24 k-tiles

// ---------------- prep: W1^T -> bf16, LINEAR [n][k] (B consumed global->reg) ----------------
__global__ __launch_bounds__(256)
void prep_w1t(const float* __restrict__ w_lin, unsigned short* __restrict__ w1t) {
  __shared__ __align__(16) unsigned short T[64][80];
  int bidk = blockIdx.x % 12, bidn = blockIdx.x / 12;
  int k0 = bidk * 64, n0 = bidn * 64;
  int tid = threadIdx.x;
#pragma unroll
  for (int p = 0; p < 16; ++p) {
    int idx = p * 256 + tid;
    int kl = idx >> 6, nl = idx & 63;
    float v = w_lin[(size_t)(k0 + kl) * Hc + (n0 + nl)];
    __bf16 bv = (__bf16)v;
    T[nl][kl] = __builtin_bit_cast(unsigned short, bv);
  }
  __syncthreads();
#pragma unroll
  for (int qq = 0; qq < 2; ++qq) {
    int q = qq * 256 + tid;
    int nl = q >> 3, c = q & 7;
    int n = n0 + nl;
    s16x8 v = *(const s16x8*)(&T[nl][c * 8]);
    *(s16x8*)(w1t + (size_t)n * Hc + k0 + c * 8) = v;
  }
}

// ---------------- cls projection (fp32 exact, bias folded) + token_inputs copy ----------------
__global__ __launch_bounds__(256)
void cls_proj_kernel(const float* __restrict__ emb, const float* __restrict__ w_lin,
                     const float* __restrict__ b_lin, float* __restrict__ out,
                     float* __restrict__ cls_proj) {
  __shared__ float cls_s[Hc];
  int b = blockIdx.x / 3, hc = blockIdx.x % 3;
  int tid = threadIdx.x;
  const float* cls = emb + (size_t)b * Sc * Hc;
  for (int i = tid; i < Hc; i += 256) cls_s[i] = cls[i];
  __syncthreads();
  int h = hc * 256 + tid;
  const float* wp = w_lin + (size_t)Hc * Hc + h;
  float p0 = 0, p1 = 0, p2 = 0, p3 = 0, p4 = 0, p5 = 0, p6 = 0, p7 = 0;
  for (int f = 0; f < Hc; f += 8) {
    p0 += cls_s[f + 0] * wp[(size_t)(f + 0) * Hc];
    p1 += cls_s[f + 1] * wp[(size_t)(f + 1) * Hc];
    p2 += cls_s[f + 2] * wp[(size_t)(f + 2) * Hc];
    p3 += cls_s[f + 3] * wp[(size_t)(f + 3) * Hc];
    p4 += cls_s[f + 4] * wp[(size_t)(f + 4) * Hc];
    p5 += cls_s[f + 5] * wp[(size_t)(f + 5) * Hc];
    p6 += cls_s[f + 6] * wp[(size_t)(f + 6) * Hc];
    p7 += cls_s[f + 7] * wp[(size_t)(f + 7) * Hc];
  }
  float acc = b_lin[h] + (((p0 + p1) + (p2 + p3)) + ((p4 + p5) + (p6 + p7)));
  cls_proj[b * Hc + h] = acc;
  out[b * Hc + h] = cls_s[h];
}

// ---------------- fused span-max + GEMM + epilogue: BARRIER-FREE, per-wave-private ----------------
// Each wave: 64 m-rows (8 starts x 8 widths) x 128 n-cols, acc 4x8 f32x4.
// Private 4 KB LDS A-tile (single-buffered; wave program order is the only sync).
// No s_barrier / no manual waitcnt anywhere in the K-loop.
__global__ __launch_bounds__(256, 2)
void span_gemm(const float* __restrict__ emb, const unsigned short* __restrict__ w1t,
               const float* __restrict__ cls_proj, const float* __restrict__ w_lin,
               float* __restrict__ out) {
  __shared__ __align__(16) unsigned short Ald[4][2048]; // 4 waves x 4 KB

  // bijective XCD-chunked swizzle: 1536 = 8 x 192
  int wg = blockIdx.x;
  int wgid = (wg & 7) * 192 + (wg >> 3);
  int n_t = wgid % 6, mt_blk = wgid / 6;   // 6 n-tiles x 256 m-blocks
  int b = mt_blk >> 4;                     // 16 m-blocks per batch
  int tid = threadIdx.x;
  int wid = tid >> 6, lane = tid & 63;
  int lq = lane >> 4, lr = lane & 15;
  int n0 = n_t << 7;
  int s_loc0 = ((mt_blk & 15) << 5) + (wid << 3); // wave's first start (batch-local, 0..504)

  const char* embC = (const char*)(emb + (size_t)b * Sc * Hc);
  char* Aw = (char*)Ald[wid];

  // build roles: start i = lane>>3 (0..7), k-quad kq = lane&7 (4 floats)
  int bi = lane >> 3, kq = lane & 7;
  uint32_t rowoff[8];
#pragma unroll
  for (int t = 0; t < 8; ++t) {
    int r = s_loc0 + bi + t;
    if (r > 511) r = 511; // clamped rows feed only discarded outputs
    rowoff[t] = (uint32_t)r * (Hc * 4) + kq * 16;
  }
  // A-write: m = bi*8+t, byte = m*64 + (((kq>>1)^(t&3))<<4) + ((kq&1)<<3)
  int awbase = (bi << 9) + ((kq & 1) << 3);

  // B fragment base: n-row = n0 + ni*16 + lr, k-chunk lq*8 (linear w1t)
  const unsigned short* bb = w1t + (size_t)(n0 + lr) * Hc + (lq << 3);

  f32x4 acc[4][8];
  f32x4 zer = {0.f, 0.f, 0.f, 0.f};
#pragma unroll
  for (int i = 0; i < 4; ++i)
#pragma unroll
    for (int j = 0; j < 8; ++j) acc[i][j] = zer;

  // af read offsets: m = mi*16+lr -> byte = mi*1024 + lr*64 + ((lq^(lr&3))<<4)
  int arbase = (lr << 6) + (((lq ^ (lr & 3))) << 4);

  for (int kt = 0; kt < KS; ++kt) {
    int kb = kt << 7; // byte offset into emb k-range (32 floats)

    // ---- load emb rows (L2-resident; independent, hoistable) ----
    f32x4 rv[8];
#pragma unroll
    for (int t = 0; t < 8; ++t)
      rv[t] = *(const f32x4*)(embC + rowoff[t] + kb);

    // ---- load B fragments for this k-tile (independent, hoistable) ----
    bf16x8 bfr[8];
#pragma unroll
    for (int ni = 0; ni < 8; ++ni)
      bfr[ni] = *(const bf16x8*)(const void*)(bb + ni * 16 * Hc + kt * 32);

    // ---- build A: running max widths 1..8, pack bf16, private ds_write ----
    {
      f32x4 cm = rv[0];
#pragma unroll
      for (int t = 0; t < 8; ++t) {
        if (t) {
          cm[0] = fmaxf(cm[0], rv[t][0]);
          cm[1] = fmaxf(cm[1], rv[t][1]);
          cm[2] = fmaxf(cm[2], rv[t][2]);
          cm[3] = fmaxf(cm[3], rv[t][3]);
        }
        bf16x4 p;
        p[0] = (__bf16)cm[0]; p[1] = (__bf16)cm[1];
        p[2] = (__bf16)cm[2]; p[3] = (__bf16)cm[3];
        int off = awbase + (t << 6) + ((((kq >> 1) ^ t) & 3) << 4);
        *(uint2*)(Aw + off) = __builtin_bit_cast(uint2, p);
      }
    }

    // ---- read A fragments (compiler inserts the lgkm wait) and MFMA ----
    bf16x8 af[4];
#pragma unroll
    for (int mi = 0; mi < 4; ++mi)
      af[mi] = *(const bf16x8*)(Aw + (mi << 10) + arbase);
#pragma unroll
    for (int mi = 0; mi < 4; ++mi)
#pragma unroll
      for (int ni = 0; ni < 8; ++ni)
        acc[mi][ni] = __builtin_amdgcn_mfma_f32_16x16x32_bf16(af[mi], bfr[ni], acc[mi][ni], 0, 0, 0);
  }

  // ---- epilogue: add cls_proj + width*w_last, map padded rows -> span index, store ----
  const float* w2p = w_lin + (size_t)(2 * Hc) * Hc;
  float* outp = out + Bc * Hc;
  int swb = s_loc0 << 3; // batch-local padded-row base (0..4032)
  float cp[8], w2[8];
#pragma unroll
  for (int ni = 0; ni < 8; ++ni) {
    int h = n0 + (ni << 4) + lr;
    cp[ni] = cls_proj[b * Hc + h];
    w2[ni] = w2p[h];
  }
  int hbase = n0 + lr;
#pragma unroll
  for (int mi = 0; mi < 4; ++mi) {
#pragma unroll
    for (int j = 0; j < 4; ++j) {
      int m = (mi << 4) + (lq << 2) + j;
      int sw = swb + m;
      int s = sw >> 3, w = (sw & 7) + 1;
      if (s + w <= 512) {
        int nsp = (s <= 504) ? sw
                             : (NSPAN - (((512 - s) * (513 - s)) >> 1) + w - 1);
        float* rowp = outp + ((size_t)b * NSPAN + nsp) * Hc + hbase;
        float wf = (float)w;
#pragma unroll
        for (int ni = 0; ni < 8; ++ni)
          rowp[ni << 4] = acc[mi][ni][j] + cp[ni] + wf * w2[ni];
      }
    }
  }
}

extern "C" void kernel_launch(void* const* d_in, const int* in_sizes, int n_in,
                              void* d_out, int out_size, void* d_ws, size_t ws_size,
                              hipStream_t stream) {
  const float* emb = (const float*)d_in[0];
  const float* w_lin = (const float*)d_in[1];
  const float* b_lin = (const float*)d_in[2];
  unsigned short* w1t = (unsigned short*)d_ws;
  float* cls_proj = (float*)((char*)d_ws + (size_t)Hc * Hc * 2);
  float* out = (float*)d_out;

  hipLaunchKernelGGL(prep_w1t, dim3(144), dim3(256), 0, stream, w_lin, w1t);
  hipLaunchKernelGGL(cls_proj_kernel, dim3(48), dim3(256), 0, stream, emb, w_lin, b_lin, out, cls_proj);
  hipLaunchKernelGGL(span_gemm, dim3(1536), dim3(256), 0, stream, emb, w1t, cls_proj, w_lin, out);
}

// Round 9
// 153.790 us; speedup vs baseline: 1.3861x; 1.3861x over previous
//
#include <hip/hip_runtime.h>
#include <hip/hip_bf16.h>
#include <stdint.h>

#define AS1 __attribute__((address_space(1)))
#define AS3 __attribute__((address_space(3)))

typedef float  f32x4  __attribute__((ext_vector_type(4)));
typedef __bf16 bf16x8 __attribute__((ext_vector_type(8)));
typedef __bf16 bf16x4 __attribute__((ext_vector_type(4)));
typedef short  s16x8  __attribute__((ext_vector_type(8)));

static constexpr int Bc = 16, Sc = 512, Hc = 768, NSPAN = 4068;

// ================= prep: W1^T -> bf16; swz=1: 64B-group chunk swizzle (c^(n&3)); swz=0: linear =================
__global__ __launch_bounds__(256)
void prep_w1t(const float* __restrict__ w_lin, unsigned short* __restrict__ w1t, int swz) {
  __shared__ __align__(16) unsigned short T[64][80];
  int bidk = blockIdx.x % 12, bidn = blockIdx.x / 12;
  int k0 = bidk * 64, n0 = bidn * 64;
  int tid = threadIdx.x;
#pragma unroll
  for (int p = 0; p < 16; ++p) {
    int idx = p * 256 + tid;
    int kl = idx >> 6, nl = idx & 63;
    float v = w_lin[(size_t)(k0 + kl) * Hc + (n0 + nl)];
    __bf16 bv = (__bf16)v;
    T[nl][kl] = __builtin_bit_cast(unsigned short, bv);
  }
  __syncthreads();
#pragma unroll
  for (int qq = 0; qq < 2; ++qq) {
    int q = qq * 256 + tid;
    int nl = q >> 3, cc = q & 7;           // chunk cc within this 64-k block (8 chunks)
    int n = n0 + nl;
    s16x8 v = *(const s16x8*)(&T[nl][cc * 8]);
    size_t off;
    if (swz) {
      int q8 = (k0 >> 3) + cc;             // global 8-elem chunk index 0..95
      off = (size_t)n * 1536 + (size_t)(q8 >> 2) * 64 + (size_t)((q8 & 3) ^ (n & 3)) * 16;
    } else {
      off = (size_t)n * 1536 + (size_t)k0 * 2 + (size_t)cc * 16;
    }
    *(s16x8*)((char*)w1t + off) = v;
  }
}

// ================= cls projection (fp32 exact, bias folded) + token_inputs copy =================
__global__ __launch_bounds__(256)
void cls_proj_kernel(const float* __restrict__ emb, const float* __restrict__ w_lin,
                     const float* __restrict__ b_lin, float* __restrict__ out,
                     float* __restrict__ cls_proj) {
  __shared__ float cls_s[Hc];
  int b = blockIdx.x / 3, hc = blockIdx.x % 3;
  int tid = threadIdx.x;
  const float* cls = emb + (size_t)b * Sc * Hc;
  for (int i = tid; i < Hc; i += 256) cls_s[i] = cls[i];
  __syncthreads();
  int h = hc * 256 + tid;
  const float* wp = w_lin + (size_t)Hc * Hc + h;
  float p0 = 0, p1 = 0, p2 = 0, p3 = 0, p4 = 0, p5 = 0, p6 = 0, p7 = 0;
  for (int f = 0; f < Hc; f += 8) {
    p0 += cls_s[f + 0] * wp[(size_t)(f + 0) * Hc];
    p1 += cls_s[f + 1] * wp[(size_t)(f + 1) * Hc];
    p2 += cls_s[f + 2] * wp[(size_t)(f + 2) * Hc];
    p3 += cls_s[f + 3] * wp[(size_t)(f + 3) * Hc];
    p4 += cls_s[f + 4] * wp[(size_t)(f + 4) * Hc];
    p5 += cls_s[f + 5] * wp[(size_t)(f + 5) * Hc];
    p6 += cls_s[f + 6] * wp[(size_t)(f + 6) * Hc];
    p7 += cls_s[f + 7] * wp[(size_t)(f + 7) * Hc];
  }
  float acc = b_lin[h] + (((p0 + p1) + (p2 + p3)) + ((p4 + p5) + (p6 + p7)));
  cls_proj[b * Hc + h] = acc;
  out[b * Hc + h] = cls_s[h];
}

// ================= pass 1: materialize A = span running-max, bf16, 64B-group swizzled =================
// Row m = (b*512+s)*8 + t holds max(emb[s..s+t]) cast bf16. Chunk q8 (8 k-values, 16B) stored at
// byte (q8>>2)*64 + ((q8&3)^(m&3))*16 within the 1536B row; m&3 == t&3.
__global__ __launch_bounds__(256)
void build_a(const float* __restrict__ emb, unsigned short* __restrict__ a_ws) {
  int blk = blockIdx.x;            // 1024 = 16 b x 64 s-blocks
  int b = blk >> 6, sb = blk & 63;
  int tid = threadIdx.x;
  int si = tid >> 5, kc = tid & 31;
  int s = (sb << 3) + si;
  const char* embB = (const char*)(emb + (size_t)b * Sc * Hc);
  uint32_t roff[8];
#pragma unroll
  for (int t = 0; t < 8; ++t) {
    int r = s + t;
    if (r > 511) r = 511;          // rows feed only discarded outputs
    roff[t] = (uint32_t)r * (Hc * 4);
  }
  char* obase = (char*)a_ws + (size_t)((b * 512 + s) * 8) * 1536;
#pragma unroll
  for (int j = 0; j < 3; ++j) {
    int q8 = kc + (j << 5);        // chunk index 0..95
    uint32_t srcoff = (uint32_t)q8 * 32;
    f32x4 c0, c1;
#pragma unroll
    for (int t = 0; t < 8; ++t) {
      f32x4 a0 = *(const f32x4*)(embB + roff[t] + srcoff);
      f32x4 a1 = *(const f32x4*)(embB + roff[t] + srcoff + 16);
      if (t == 0) { c0 = a0; c1 = a1; }
      else {
        c0[0] = fmaxf(c0[0], a0[0]); c0[1] = fmaxf(c0[1], a0[1]);
        c0[2] = fmaxf(c0[2], a0[2]); c0[3] = fmaxf(c0[3], a0[3]);
        c1[0] = fmaxf(c1[0], a1[0]); c1[1] = fmaxf(c1[1], a1[1]);
        c1[2] = fmaxf(c1[2], a1[2]); c1[3] = fmaxf(c1[3], a1[3]);
      }
      bf16x8 p;
      p[0] = (__bf16)c0[0]; p[1] = (__bf16)c0[1]; p[2] = (__bf16)c0[2]; p[3] = (__bf16)c0[3];
      p[4] = (__bf16)c1[0]; p[5] = (__bf16)c1[1]; p[6] = (__bf16)c1[2]; p[7] = (__bf16)c1[3];
      size_t doff = (size_t)t * 1536 + (size_t)(q8 >> 2) * 64 + (size_t)((q8 & 3) ^ (t & 3)) * 16;
      *(bf16x8*)(obase + doff) = p;
    }
  }
}

// ================= pass 2: deep-pipelined GEMM (256x256 tile, BK=32, 4-slot LDS ring) =================
// 8 waves 2Mx4N (128x64 each). Ring slot kt&3 (A 16KB | B 16KB). Stage kt+3 while computing kt.
// Counted vmcnt(8) at K-tile boundaries (never 0 in main loop).
__global__ __launch_bounds__(512, 1)
void gemm_pipe(const unsigned short* __restrict__ a_ws, const unsigned short* __restrict__ w1t,
               const float* __restrict__ cls_proj, const float* __restrict__ w_lin,
               float* __restrict__ out) {
  extern __shared__ __align__(16) char ldsb[]; // 4 x 32768 = 131072 B

  int wg = blockIdx.x;
  int wgid = (wg & 7) * 96 + (wg >> 3);        // bijective XCD swizzle, 768 = 8 x 96
  int tile_n = wgid % 3, tile_m = wgid / 3;    // 256 m-tiles x 3 n-tiles
  int b = tile_m >> 4;
  int n0 = tile_n << 8;
  int tid = threadIdx.x;
  int wid = tid >> 6, lane = tid & 63;
  int wave_m = wid >> 2, wave_n = wid & 3;
  int lq = lane >> 4, lr = lane & 15;

  const char* aw = (const char*)a_ws + ((size_t)tile_m << 8) * 1536;
  const char* bw = (const char*)w1t + (size_t)n0 * 1536;
  int srow = tid >> 2, schunk = tid & 3;

  // epilogue constants FIRST (oldest vmem; drained by prologue vmcnt)
  const float* w2p = w_lin + (size_t)(2 * Hc) * Hc;
  float cp[4], w2[4];
#pragma unroll
  for (int ni = 0; ni < 4; ++ni) {
    int h = n0 + (wave_n << 6) + (ni << 4) + lr;
    cp[ni] = cls_proj[b * Hc + h];
    w2[ni] = w2p[h];
  }

  f32x4 acc[8][4];
  f32x4 zer = {0.f, 0.f, 0.f, 0.f};
#pragma unroll
  for (int i = 0; i < 8; ++i)
#pragma unroll
    for (int j = 0; j < 4; ++j) acc[i][j] = zer;

  bf16x8 bfr[4];

#define SB __builtin_amdgcn_sched_barrier(0)

#define STAGE_A(kt) {                                                          \
    const char* s_ = aw + (size_t)srow * 1536 + (size_t)(kt) * 64 + (schunk << 4); \
    char* d_ = ldsb + (((kt) & 3) << 15) + (tid << 4);                         \
    __builtin_amdgcn_global_load_lds((const AS1 uint32_t*)s_, (AS3 uint32_t*)d_, 16, 0, 0); \
    __builtin_amdgcn_global_load_lds((const AS1 uint32_t*)(s_ + 128 * 1536), (AS3 uint32_t*)(d_ + 8192), 16, 0, 0); }

#define STAGE_B(kt) {                                                          \
    const char* s_ = bw + (size_t)srow * 1536 + (size_t)(kt) * 64 + (schunk << 4); \
    char* d_ = ldsb + (((kt) & 3) << 15) + 16384 + (tid << 4);                 \
    __builtin_amdgcn_global_load_lds((const AS1 uint32_t*)s_, (AS3 uint32_t*)d_, 16, 0, 0); \
    __builtin_amdgcn_global_load_lds((const AS1 uint32_t*)(s_ + 128 * 1536), (AS3 uint32_t*)(d_ + 8192), 16, 0, 0); }

#define PH0(kt, DOSTAGE) {                                                     \
    const char* Ab_ = ldsb + (((kt) & 3) << 15);                               \
    const char* Bb_ = Ab_ + 16384;                                             \
    _Pragma("unroll") for (int ni = 0; ni < 4; ++ni) {                         \
      int n = (wave_n << 6) + (ni << 4) + lr;                                  \
      bfr[ni] = *(const bf16x8*)(Bb_ + n * 64 + ((lq ^ (n & 3)) << 4));        \
    }                                                                          \
    bf16x8 af[4];                                                              \
    _Pragma("unroll") for (int mi = 0; mi < 4; ++mi) {                         \
      int m = (wave_m << 7) + (mi << 4) + lr;                                  \
      af[mi] = *(const bf16x8*)(Ab_ + m * 64 + ((lq ^ (m & 3)) << 4));         \
    }                                                                          \
    if (DOSTAGE) { STAGE_A((kt) + 3); }                                        \
    SB; __builtin_amdgcn_s_barrier(); SB;                                      \
    __builtin_amdgcn_s_setprio(1);                                             \
    _Pragma("unroll") for (int mi = 0; mi < 4; ++mi)                           \
      _Pragma("unroll") for (int ni = 0; ni < 4; ++ni)                         \
        acc[mi][ni] = __builtin_amdgcn_mfma_f32_16x16x32_bf16(af[mi], bfr[ni], acc[mi][ni], 0, 0, 0); \
    __builtin_amdgcn_s_setprio(0);                                             \
    __builtin_amdgcn_s_barrier(); }

#define PH1(kt, DOSTAGE, WAITASM) {                                            \
    const char* Ab_ = ldsb + (((kt) & 3) << 15);                               \
    bf16x8 af[4];                                                              \
    _Pragma("unroll") for (int mi = 0; mi < 4; ++mi) {                         \
      int m = (wave_m << 7) + 64 + (mi << 4) + lr;                             \
      af[mi] = *(const bf16x8*)(Ab_ + m * 64 + ((lq ^ (m & 3)) << 4));         \
    }                                                                          \
    if (DOSTAGE) { STAGE_B((kt) + 3); }                                        \
    SB; __builtin_amdgcn_s_barrier(); SB;                                      \
    __builtin_amdgcn_s_setprio(1);                                             \
    _Pragma("unroll") for (int mi = 0; mi < 4; ++mi)                           \
      _Pragma("unroll") for (int ni = 0; ni < 4; ++ni)                         \
        acc[4 + mi][ni] = __builtin_amdgcn_mfma_f32_16x16x32_bf16(af[mi], bfr[ni], acc[4 + mi][ni], 0, 0, 0); \
    __builtin_amdgcn_s_setprio(0);                                             \
    SB; asm volatile(WAITASM ::: "memory"); SB;                                \
    __builtin_amdgcn_s_barrier(); }

  // ---- prologue: stage kt 0,1,2 (12 gll, in-order); wait oldest (cls + kt0) ----
  STAGE_A(-3 + 3); STAGE_B(0);  // kt0
  STAGE_A(1 - 3 + 3); // placeholder comment-free below
  // (explicit, in order:)
  // kt1
  {
    const char* s_ = aw + (size_t)srow * 1536 + (size_t)1 * 64 + (schunk << 4);
    char* d_ = ldsb + ((1 & 3) << 15) + (tid << 4);
    __builtin_amdgcn_global_load_lds((const AS1 uint32_t*)s_, (AS3 uint32_t*)d_, 16, 0, 0);
    __builtin_amdgcn_global_load_lds((const AS1 uint32_t*)(s_ + 128 * 1536), (AS3 uint32_t*)(d_ + 8192), 16, 0, 0);
  }
  STAGE_B(1);
  {
    const char* s_ = aw + (size_t)srow * 1536 + (size_t)2 * 64 + (schunk << 4);
    char* d_ = ldsb + ((2 & 3) << 15) + (tid << 4);
    __builtin_amdgcn_global_load_lds((const AS1 uint32_t*)s_, (AS3 uint32_t*)d_, 16, 0, 0);
    __builtin_amdgcn_global_load_lds((const AS1 uint32_t*)(s_ + 128 * 1536), (AS3 uint32_t*)(d_ + 8192), 16, 0, 0);
  }
  STAGE_B(2);
  SB; asm volatile("s_waitcnt vmcnt(8)" ::: "memory"); SB;
  __builtin_amdgcn_s_barrier(); SB;

  // ---- main loop: kt = 0..20 stage kt+3, boundary vmcnt(8) ----
  for (int kt = 0; kt < 21; ++kt) {
    PH0(kt, 1);
    PH1(kt, 1, "s_waitcnt vmcnt(8)");
  }
  // ---- tail: kt 21 (vmcnt 4), 22 (vmcnt 0), 23 (no wait) ----
  PH0(21, 0); PH1(21, 0, "s_waitcnt vmcnt(4)");
  PH0(22, 0); PH1(22, 0, "s_waitcnt vmcnt(0)");
  PH0(23, 0); PH1(23, 0, "s_nop 0");

  // ---- epilogue ----
  float* outp = out + Bc * Hc;
  int swb = (tile_m & 15) << 8;
  int hbase = n0 + (wave_n << 6) + lr;
#pragma unroll
  for (int mi = 0; mi < 8; ++mi) {
#pragma unroll
    for (int j = 0; j < 4; ++j) {
      int m = (wave_m << 7) + (mi << 4) + (lq << 2) + j;
      int sw = swb + m;
      int s = sw >> 3, w = (sw & 7) + 1;
      if (s + w <= 512) {
        int nsp = (s <= 504) ? sw
                             : (NSPAN - (((512 - s) * (513 - s)) >> 1) + w - 1);
        float* rowp = outp + ((size_t)b * NSPAN + nsp) * Hc + hbase;
        float wf = (float)w;
#pragma unroll
        for (int ni = 0; ni < 4; ++ni)
          rowp[ni << 4] = acc[mi][ni][j] + cp[ni] + wf * w2[ni];
      }
    }
  }
}

// ================= FALLBACK (R7): fused span-max + GEMM, linear w1t, used if ws too small =================
__global__ __launch_bounds__(512, 2)
void span_gemm_fused(const float* __restrict__ emb, const unsigned short* __restrict__ w1t,
                     const float* __restrict__ cls_proj, const float* __restrict__ w_lin,
                     float* __restrict__ out) {
  __shared__ __align__(16) unsigned short Ald[2][256 * 64];
  int wg = blockIdx.x;
  int wgid = (wg & 7) * 96 + (wg >> 3);
  int tile_n = wgid % 3, tile_m = wgid / 3;
  int b = tile_m >> 4;
  int s0 = (tile_m & 15) << 5;
  int n0 = tile_n << 8;
  int tid = threadIdx.x;
  int wid = tid >> 6, lane = tid & 63;
  int wave_m = wid >> 2, wave_n = wid & 3;
  int lq = lane >> 4, lr = lane & 15;
  const char* embC = (const char*)(emb + (size_t)b * Sc * Hc);
  int bi = tid >> 4, bkq = tid & 15;
  uint32_t rowoff[8];
#pragma unroll
  for (int t = 0; t < 8; ++t) {
    int r = s0 + bi + t;
    if (r > 511) r = 511;
    rowoff[t] = (uint32_t)r * (Hc * 4) + bkq * 16;
  }
  int awbase = (bi << 10) + ((bkq & 1) << 3);
  const unsigned short* bb = w1t + (size_t)(n0 + (wave_n << 6) + lr) * Hc + (lq << 3);
  f32x4 acc[8][4];
  f32x4 zer = {0.f, 0.f, 0.f, 0.f};
#pragma unroll
  for (int i = 0; i < 8; ++i)
#pragma unroll
    for (int j = 0; j < 4; ++j) acc[i][j] = zer;
  f32x4 rv[8];
  f32x4 cm;
  bf16x8 bfrA[4], bfrB[4];
#define FLOAD_RV(koff) _Pragma("unroll") for (int t = 0; t < 8; ++t) rv[t] = *(const f32x4*)(embC + rowoff[t] + (koff));
#define FLOAD_BFR(dst, koff) _Pragma("unroll") for (int ni = 0; ni < 4; ++ni) dst[ni] = *(const bf16x8*)(const void*)(bb + (size_t)ni * 16 * Hc + (koff));
#define FBUILD_T(an, t) { \
    if ((t) == 0) cm = rv[0]; \
    else { cm[0] = fmaxf(cm[0], rv[t][0]); cm[1] = fmaxf(cm[1], rv[t][1]); cm[2] = fmaxf(cm[2], rv[t][2]); cm[3] = fmaxf(cm[3], rv[t][3]); } \
    bf16x4 p; p[0] = (__bf16)cm[0]; p[1] = (__bf16)cm[1]; p[2] = (__bf16)cm[2]; p[3] = (__bf16)cm[3]; \
    int off = awbase + ((t) << 7) + (((bkq >> 1) ^ (t)) << 4); \
    *(uint2*)((an) + off) = __builtin_bit_cast(uint2, p); }
#define FQUAD(ab, mh, kk, bfr) { \
    bf16x8 af[4]; int cf = ((kk) << 2) + lq; \
    _Pragma("unroll") for (int mi = 0; mi < 4; ++mi) { \
      int m = (wave_m << 7) + ((((mh) << 2) + mi) << 4) + lr; \
      af[mi] = *(const bf16x8*)((ab) + (m << 7) + ((cf ^ (m & 7)) << 4)); } \
    __builtin_amdgcn_s_setprio(1); \
    _Pragma("unroll") for (int mi = 0; mi < 4; ++mi) \
      _Pragma("unroll") for (int ni = 0; ni < 4; ++ni) \
        acc[((mh) << 2) + mi][ni] = __builtin_amdgcn_mfma_f32_16x16x32_bf16(af[mi], bfr[ni], acc[((mh) << 2) + mi][ni], 0, 0, 0); \
    __builtin_amdgcn_s_setprio(0); }
  FLOAD_RV(0);
  {
    char* an0 = (char*)Ald[0];
#pragma unroll
    for (int t = 0; t < 8; ++t) FBUILD_T(an0, t);
  }
  FLOAD_BFR(bfrA, 0);
  FLOAD_RV(256);
  asm volatile("s_waitcnt lgkmcnt(0)" ::: "memory");
  __builtin_amdgcn_sched_barrier(0);
  __builtin_amdgcn_s_barrier();
  for (int kt = 0; kt < 12; ++kt) {
    int cur = kt & 1, nb = cur ^ 1;
    const char* ab = (const char*)Ald[cur];
    char* an = (char*)Ald[nb];
    FLOAD_BFR(bfrB, kt * 64 + 32);
    FQUAD(ab, 0, 0, bfrA);
    __builtin_amdgcn_sched_barrier(0);
    FQUAD(ab, 1, 0, bfrA);
    __builtin_amdgcn_sched_barrier(0);
    if (kt + 1 < 12) {
      FLOAD_BFR(bfrA, (kt + 1) * 64);
#pragma unroll
      for (int t = 0; t < 4; ++t) FBUILD_T(an, t);
    }
    FQUAD(ab, 0, 1, bfrB);
    __builtin_amdgcn_sched_barrier(0);
    if (kt + 1 < 12) {
#pragma unroll
      for (int t = 4; t < 8; ++t) FBUILD_T(an, t);
    }
    if (kt + 2 < 12) FLOAD_RV((kt + 2) * 256);
    FQUAD(ab, 1, 1, bfrB);
    if (kt + 1 < 12) {
      asm volatile("s_waitcnt lgkmcnt(0)" ::: "memory");
      __builtin_amdgcn_sched_barrier(0);
      __builtin_amdgcn_s_barrier();
      __builtin_amdgcn_sched_barrier(0);
    }
  }
  const float* w2p = w_lin + (size_t)(2 * Hc) * Hc;
  float* outp = out + Bc * Hc;
  int swb = (tile_m & 15) << 8;
  float cp[4], w2[4];
#pragma unroll
  for (int ni = 0; ni < 4; ++ni) {
    int h = n0 + (wave_n << 6) + (ni << 4) + lr;
    cp[ni] = cls_proj[b * Hc + h];
    w2[ni] = w2p[h];
  }
  int hbase = n0 + (wave_n << 6) + lr;
#pragma unroll
  for (int mi = 0; mi < 8; ++mi) {
#pragma unroll
    for (int j = 0; j < 4; ++j) {
      int m = (wave_m << 7) + (mi << 4) + (lq << 2) + j;
      int sw = swb + m;
      int s = sw >> 3, w = (sw & 7) + 1;
      if (s + w <= 512) {
        int nsp = (s <= 504) ? sw : (NSPAN - (((512 - s) * (513 - s)) >> 1) + w - 1);
        float* rowp = outp + ((size_t)b * NSPAN + nsp) * Hc + hbase;
        float wf = (float)w;
#pragma unroll
        for (int ni = 0; ni < 4; ++ni)
          rowp[ni << 4] = acc[mi][ni][j] + cp[ni] + wf * w2[ni];
      }
    }
  }
}

extern "C" void kernel_launch(void* const* d_in, const int* in_sizes, int n_in,
                              void* d_out, int out_size, void* d_ws, size_t ws_size,
                              hipStream_t stream) {
  const float* emb = (const float*)d_in[0];
  const float* w_lin = (const float*)d_in[1];
  const float* b_lin = (const float*)d_in[2];
  unsigned short* w1t = (unsigned short*)d_ws;                          // 1,179,648 B
  float* cls_proj = (float*)((char*)d_ws + 1179648);                    // 49,152 B
  unsigned short* a_ws = (unsigned short*)((char*)d_ws + 1228800);      // 100,663,296 B
  float* out = (float*)d_out;

  size_t need = 1228800ull + 100663296ull;
  if (ws_size >= need) {
    hipLaunchKernelGGL(prep_w1t, dim3(144), dim3(256), 0, stream, w_lin, w1t, 1);
    hipLaunchKernelGGL(cls_proj_kernel, dim3(48), dim3(256), 0, stream, emb, w_lin, b_lin, out, cls_proj);
    hipLaunchKernelGGL(build_a, dim3(1024), dim3(256), 0, stream, emb, a_ws);
    static int attr_set = 0;
    if (!attr_set) {
      hipFuncSetAttribute((const void*)gemm_pipe, hipFuncAttributeMaxDynamicSharedMemorySize, 131072);
      attr_set = 1;
    }
    hipLaunchKernelGGL(gemm_pipe, dim3(768), dim3(512), 131072, stream, a_ws, w1t, cls_proj, w_lin, out);
  } else {
    hipLaunchKernelGGL(prep_w1t, dim3(144), dim3(256), 0, stream, w_lin, w1t, 0);
    hipLaunchKernelGGL(cls_proj_kernel, dim3(48), dim3(256), 0, stream, emb, w_lin, b_lin, out, cls_proj);
    hipLaunchKernelGGL(span_gemm_fused, dim3(768), dim3(512), 0, stream, emb, w1t, cls_proj, w_lin, out);
  }
}